// Round 1
// baseline (1795.049 us; speedup 1.0000x reference)
//
#include <hip/hip_runtime.h>
#include <math.h>

#define N_NODES 50000
#define N_EDGES 400000
#define E_HALF  200000
#define D 128

// ---------------------------------------------------------------------------
// K1/K3: tiled fp32 GEMM  out[g] = act(x) @ W[g]   (act = relu if RELU_IN)
// x: [N,128] row-major, W: [128,128] row-major (k-major), out: [N,128].
// Block: 256 threads, 64-row tile, blockIdx.y selects which W/out pair.
// Thread tile 4 rows x 8 cols -> acc[4][8]; W staged in LDS (64KB),
// x rows staged in LDS padded to 132 floats (bank-conflict-free, 16B aligned).
// ---------------------------------------------------------------------------
template <int RELU_IN>
__global__ __launch_bounds__(256) void gemm_tile(
    const float* __restrict__ x,
    const float* __restrict__ W0, const float* __restrict__ W1,
    const float* __restrict__ W2, const float* __restrict__ W3,
    float* __restrict__ O0, float* __restrict__ O1,
    float* __restrict__ O2, float* __restrict__ O3)
{
    __shared__ float ws[D][D];        // 64 KB
    __shared__ float xs[64][132];     // 33 KB, padded: stride 132 floats

    const float* W;
    float* O;
    switch (blockIdx.y) {
        case 0:  W = W0; O = O0; break;
        case 1:  W = W1; O = O1; break;
        case 2:  W = W2; O = O2; break;
        default: W = W3; O = O3; break;
    }

    const int tid  = threadIdx.x;
    const int row0 = blockIdx.x * 64;

    // stage W (16384 floats, float4 per lane, coalesced)
    for (int i = tid * 4; i < D * D; i += 256 * 4) {
        *(float4*)&ws[0][0 + i] = *(const float4*)&W[i];
    }
    // stage x rows (guard tail rows), optional relu on load
    for (int i = tid * 4; i < 64 * D; i += 256 * 4) {
        const int row = i >> 7;        // /128
        const int col = i & 127;
        const int r   = row0 + row;
        float4 v;
        if (r < N_NODES) {
            v = *(const float4*)&x[(size_t)r * D + col];
        } else {
            v = make_float4(0.f, 0.f, 0.f, 0.f);
        }
        if (RELU_IN) {
            v.x = fmaxf(v.x, 0.f); v.y = fmaxf(v.y, 0.f);
            v.z = fmaxf(v.z, 0.f); v.w = fmaxf(v.w, 0.f);
        }
        *(float4*)&xs[row][col] = v;
    }
    __syncthreads();

    const int ty = tid >> 4;          // 0..15
    const int tx = tid & 15;          // 0..15
    const int r0 = ty * 4;
    const int c0 = tx * 8;

    float acc[4][8];
    #pragma unroll
    for (int r = 0; r < 4; ++r)
        #pragma unroll
        for (int c = 0; c < 8; ++c) acc[r][c] = 0.f;

    #pragma unroll 4
    for (int k = 0; k < D; ++k) {
        const float4 w0 = *(const float4*)&ws[k][c0];
        const float4 w1 = *(const float4*)&ws[k][c0 + 4];
        const float wv[8] = {w0.x, w0.y, w0.z, w0.w, w1.x, w1.y, w1.z, w1.w};
        #pragma unroll
        for (int r = 0; r < 4; ++r) {
            const float xv = xs[r0 + r][k];
            #pragma unroll
            for (int c = 0; c < 8; ++c)
                acc[r][c] = fmaf(xv, wv[c], acc[r][c]);
        }
    }

    #pragma unroll
    for (int r = 0; r < 4; ++r) {
        const int row = row0 + r0 + r;
        if (row < N_NODES) {
            float4 o0 = make_float4(acc[r][0], acc[r][1], acc[r][2], acc[r][3]);
            float4 o1 = make_float4(acc[r][4], acc[r][5], acc[r][6], acc[r][7]);
            *(float4*)&O[(size_t)row * D + c0]     = o0;
            *(float4*)&O[(size_t)row * D + c0 + 4] = o1;
        }
    }
}

// ---------------------------------------------------------------------------
// K2: agg scatter-add:  emb_acc[dst[e]] += h[src[e]]   (128 floats / edge)
// 32 lanes per edge, float4 per lane -> 512B coalesced gather + 4 atomics/lane
// ---------------------------------------------------------------------------
__global__ __launch_bounds__(256) void edge_scatter1(
    const int* __restrict__ src, const int* __restrict__ dst,
    const float* __restrict__ h, float* __restrict__ acc)
{
    const int t    = blockIdx.x * 256 + threadIdx.x;
    const int e    = t >> 5;
    const int lane = t & 31;
    if (e >= N_EDGES) return;
    const int s = src[e];
    const int d = dst[e];
    const float4 v = *(const float4*)&h[(size_t)s * D + lane * 4];
    float* p = &acc[(size_t)d * D + lane * 4];
    atomicAdd(p + 0, v.x);
    atomicAdd(p + 1, v.y);
    atomicAdd(p + 2, v.z);
    atomicAdd(p + 3, v.w);
}

// ---------------------------------------------------------------------------
// K4: per-edge attention:  att[e] = sigmoid( tanh(A[src]+B[dst]) . we2 + g(e) )
// 32 lanes per edge; intra-32-lane shfl_xor reduction for the dot product.
// ---------------------------------------------------------------------------
__global__ __launch_bounds__(256) void edge_logits(
    const int* __restrict__ src, const int* __restrict__ dst,
    const float* __restrict__ A, const float* __restrict__ B,
    const float* __restrict__ we2, const float* __restrict__ noise_u,
    float* __restrict__ att)
{
    const int t    = blockIdx.x * 256 + threadIdx.x;
    const int e    = t >> 5;
    const int lane = t & 31;
    if (e >= N_EDGES) return;
    const int s = src[e];
    const int d = dst[e];
    const float4 a = *(const float4*)&A[(size_t)s * D + lane * 4];
    const float4 b = *(const float4*)&B[(size_t)d * D + lane * 4];
    const float4 w = *(const float4*)&we2[lane * 4];
    float p = tanhf(a.x + b.x) * w.x + tanhf(a.y + b.y) * w.y +
              tanhf(a.z + b.z) * w.z + tanhf(a.w + b.w) * w.w;
    #pragma unroll
    for (int off = 16; off >= 1; off >>= 1)
        p += __shfl_xor(p, off, 32);
    if (lane == 0) {
        const float u = noise_u[e];
        const float z = p + logf(u) - log1pf(-u);
        att[e] = 1.f / (1.f + expf(-z));
    }
}

// ---------------------------------------------------------------------------
// K5: symmetrize + attention-weighted scatter:
//   w = 0.5*(att[e] + att[pair(e)]);  out[dst[e]] += w * hc[src[e]]
// ---------------------------------------------------------------------------
__global__ __launch_bounds__(256) void edge_scatter2(
    const int* __restrict__ src, const int* __restrict__ dst,
    const float* __restrict__ att, const float* __restrict__ hc,
    float* __restrict__ out)
{
    const int t    = blockIdx.x * 256 + threadIdx.x;
    const int e    = t >> 5;
    const int lane = t & 31;
    if (e >= N_EDGES) return;
    const int pair = (e < E_HALF) ? (e + E_HALF) : (e - E_HALF);
    const float w  = 0.5f * (att[e] + att[pair]);
    const int s = src[e];
    const int d = dst[e];
    const float4 v = *(const float4*)&hc[(size_t)s * D + lane * 4];
    float* p = &out[(size_t)d * D + lane * 4];
    atomicAdd(p + 0, w * v.x);
    atomicAdd(p + 1, w * v.y);
    atomicAdd(p + 2, w * v.z);
    atomicAdd(p + 3, w * v.w);
}

// ---------------------------------------------------------------------------
// K6: relu in place over d_out
// ---------------------------------------------------------------------------
__global__ __launch_bounds__(256) void relu_inplace(float* __restrict__ p, int n4)
{
    const int i = blockIdx.x * 256 + threadIdx.x;
    if (i >= n4) return;
    float4 v = ((float4*)p)[i];
    v.x = fmaxf(v.x, 0.f); v.y = fmaxf(v.y, 0.f);
    v.z = fmaxf(v.z, 0.f); v.w = fmaxf(v.w, 0.f);
    ((float4*)p)[i] = v;
}

extern "C" void kernel_launch(void* const* d_in, const int* in_sizes, int n_in,
                              void* d_out, int out_size, void* d_ws, size_t ws_size,
                              hipStream_t stream)
{
    const float* x      = (const float*)d_in[0];   // [50000,128]
    const float* W1     = (const float*)d_in[1];   // [128,128]
    const float* W2     = (const float*)d_in[2];   // [128,128]
    const float* We1    = (const float*)d_in[3];   // [256,128]
    const float* we2    = (const float*)d_in[4];   // [128]
    const float* Wc1    = (const float*)d_in[5];   // [128,128]
    const float* Wc2    = (const float*)d_in[6];   // [128,128]
    const float* noiseu = (const float*)d_in[7];   // [400000]
    const int*   eidx   = (const int*)d_in[8];     // [2,400000] int32

    const int* src = eidx;
    const int* dst = eidx + N_EDGES;

    float* out = (float*)d_out;                    // [50000,128] accumulator

    // workspace layout (floats)
    float* wsf = (float*)d_ws;
    float* h    = wsf;                       // [N,D]  (reused as A after K2)
    float* hc   = wsf + 6400000;             // [N,D]
    float* emb  = wsf + 12800000;            // [N,D]  x@W2 + agg accumulator
    float* Bb   = wsf + 19200000;            // [N,D]
    float* att  = wsf + 25600000;            // [E]
    // total: 26.0M floats = 104 MB

    const int row_tiles = (N_NODES + 63) / 64;   // 782

    // K1: h = x@W1, emb = x@W2, hc = x@Wc1, out = x@Wc2
    gemm_tile<0><<<dim3(row_tiles, 4), 256, 0, stream>>>(
        x, W1, W2, Wc1, Wc2, h, emb, hc, out);

    // K2: emb += segment_sum(h[src] -> dst)
    edge_scatter1<<<(N_EDGES * 32 + 255) / 256, 256, 0, stream>>>(src, dst, h, emb);

    // K3: A = relu(emb)@We1_top (overwrites h), B = relu(emb)@We1_bot
    gemm_tile<1><<<dim3(row_tiles, 2), 256, 0, stream>>>(
        emb, We1, We1 + D * D, nullptr, nullptr, h, Bb, nullptr, nullptr);

    // K4: att[e] = sigmoid(tanh(A[src]+B[dst]).we2 + gumbel(noise))
    edge_logits<<<(N_EDGES * 32 + 255) / 256, 256, 0, stream>>>(
        src, dst, h, Bb, we2, noiseu, att);

    // K5: out += segment_sum(0.5*(att+att_rev) * hc[src] -> dst)
    edge_scatter2<<<(N_EDGES * 32 + 255) / 256, 256, 0, stream>>>(
        src, dst, att, hc, out);

    // K6: out = relu(out)
    const int n4 = N_NODES * D / 4;
    relu_inplace<<<(n4 + 255) / 256, 256, 0, stream>>>(out, n4);
}

// Round 5
// 720.528 us; speedup vs baseline: 2.4913x; 2.4913x over previous
//
#include <hip/hip_runtime.h>
#include <math.h>

#define N_NODES 50000
#define N_EDGES 400000
#define E_HALF  200000
#define D 128

// ---------------------------------------------------------------------------
// gemm_multi: fp32 GEMM  O[g] = act(x) @ W[g], g = 0..NG-1 (act = relu if RELU_IN)
// x: [N,128] row-major, W: [128,128] row-major, O: [N,128].
// 256 threads, 64-row tile. x tile staged to LDS ONCE (padded stride 132),
// then loop over the NG weight matrices, staging each into LDS (64KB).
// In-place safe (O[g] == x): each block writes only rows it staged itself.
// ---------------------------------------------------------------------------
template <int NG, int RELU_IN>
__global__ __launch_bounds__(256) void gemm_multi(
    const float* __restrict__ x,
    const float* __restrict__ W0, const float* __restrict__ W1,
    const float* __restrict__ W2, const float* __restrict__ W3,
    float* __restrict__ O0, float* __restrict__ O1,
    float* __restrict__ O2, float* __restrict__ O3)
{
    __shared__ float ws[D][D];        // 64 KB
    __shared__ float xs[64][132];     // 33 KB

    const float* Wg[4] = {W0, W1, W2, W3};
    float*       Og[4] = {O0, O1, O2, O3};

    const int tid  = threadIdx.x;
    const int row0 = blockIdx.x * 64;

    // stage x tile once
    for (int i = tid * 4; i < 64 * D; i += 256 * 4) {
        const int row = i >> 7;
        const int col = i & 127;
        const int r   = row0 + row;
        float4 v;
        if (r < N_NODES) {
            v = *(const float4*)&x[(size_t)r * D + col];
        } else {
            v = make_float4(0.f, 0.f, 0.f, 0.f);
        }
        if (RELU_IN) {
            v.x = fmaxf(v.x, 0.f); v.y = fmaxf(v.y, 0.f);
            v.z = fmaxf(v.z, 0.f); v.w = fmaxf(v.w, 0.f);
        }
        *(float4*)&xs[row][col] = v;
    }

    const int ty = tid >> 4;          // 0..15
    const int tx = tid & 15;          // 0..15
    const int r0 = ty * 4;
    const int c0 = tx * 8;

    #pragma unroll
    for (int g = 0; g < NG; ++g) {
        __syncthreads();              // xs staged / prev iter's ws reads done
        const float* W = Wg[g];
        for (int i = tid * 4; i < D * D; i += 256 * 4) {
            *(float4*)&ws[0][0 + i] = *(const float4*)&W[i];
        }
        __syncthreads();

        float acc[4][8];
        #pragma unroll
        for (int r = 0; r < 4; ++r)
            #pragma unroll
            for (int c = 0; c < 8; ++c) acc[r][c] = 0.f;

        #pragma unroll 4
        for (int k = 0; k < D; ++k) {
            const float4 w0 = *(const float4*)&ws[k][c0];
            const float4 w1 = *(const float4*)&ws[k][c0 + 4];
            const float wv[8] = {w0.x, w0.y, w0.z, w0.w, w1.x, w1.y, w1.z, w1.w};
            #pragma unroll
            for (int r = 0; r < 4; ++r) {
                const float xv = xs[r0 + r][k];
                #pragma unroll
                for (int c = 0; c < 8; ++c)
                    acc[r][c] = fmaf(xv, wv[c], acc[r][c]);
            }
        }

        float* O = Og[g];
        #pragma unroll
        for (int r = 0; r < 4; ++r) {
            const int row = row0 + r0 + r;
            if (row < N_NODES) {
                float4 o0 = make_float4(acc[r][0], acc[r][1], acc[r][2], acc[r][3]);
                float4 o1 = make_float4(acc[r][4], acc[r][5], acc[r][6], acc[r][7]);
                *(float4*)&O[(size_t)row * D + c0]     = o0;
                *(float4*)&O[(size_t)row * D + c0 + 4] = o1;
            }
        }
    }
}

// ---------------------------------------------------------------------------
// CSR build: zero -> histogram -> single-block scan -> bucket scatter
// ---------------------------------------------------------------------------
__global__ __launch_bounds__(256) void zero_kernel(int* __restrict__ p, int n)
{
    const int i = blockIdx.x * 256 + threadIdx.x;
    if (i < n) p[i] = 0;
}

__global__ __launch_bounds__(256) void hist_kernel(
    const int* __restrict__ dst, int* __restrict__ cnt)
{
    const int e = blockIdx.x * 256 + threadIdx.x;
    if (e < N_EDGES) atomicAdd(&cnt[dst[e]], 1);
}

#define SCAN_T 1024
__global__ __launch_bounds__(SCAN_T) void scan_kernel(
    const int* __restrict__ cnt, int* __restrict__ off, int* __restrict__ cursor)
{
    __shared__ int part[SCAN_T];
    const int tid  = threadIdx.x;
    const int per  = (N_NODES + SCAN_T - 1) / SCAN_T;   // 49
    const int base = tid * per;
    int s = 0;
    for (int i = 0; i < per; ++i) {
        const int idx = base + i;
        if (idx < N_NODES) s += cnt[idx];
    }
    part[tid] = s;
    __syncthreads();
    for (int d = 1; d < SCAN_T; d <<= 1) {
        const int v = (tid >= d) ? part[tid - d] : 0;
        __syncthreads();
        part[tid] += v;
        __syncthreads();
    }
    int run = part[tid] - s;   // exclusive prefix
    for (int i = 0; i < per; ++i) {
        const int idx = base + i;
        if (idx < N_NODES) {
            off[idx]    = run;
            cursor[idx] = run;
            run += cnt[idx];
        }
    }
    if (tid == SCAN_T - 1) off[N_NODES] = run;
}

__global__ __launch_bounds__(256) void bucket_kernel(
    const int* __restrict__ src, const int* __restrict__ dst,
    int* __restrict__ cursor, int* __restrict__ csr_src, int* __restrict__ csr_eid)
{
    const int e = blockIdx.x * 256 + threadIdx.x;
    if (e >= N_EDGES) return;
    const int pos = atomicAdd(&cursor[dst[e]], 1);
    csr_src[pos] = src[e];
    csr_eid[pos] = e;
}

// ---------------------------------------------------------------------------
// gather_sum: emb[d] += sum_{e: dst=d} h[src[e]]   (one wave/node, float2/lane)
// ---------------------------------------------------------------------------
__global__ __launch_bounds__(256) void gather_sum(
    const int* __restrict__ off, const int* __restrict__ csr_src,
    const float* __restrict__ h, float* __restrict__ emb)
{
    const int t    = blockIdx.x * 256 + threadIdx.x;
    const int node = t >> 6;
    const int lane = t & 63;
    if (node >= N_NODES) return;
    const int beg = off[node];
    const int end = off[node + 1];
    const size_t o = (size_t)node * D + lane * 2;
    float2 acc = *(const float2*)&emb[o];
    for (int j = beg; j < end; ++j) {
        const int s = csr_src[j];
        const float2 v = *(const float2*)&h[(size_t)s * D + lane * 2];
        acc.x += v.x; acc.y += v.y;
    }
    *(float2*)&emb[o] = acc;
}

// ---------------------------------------------------------------------------
// gather_watt_relu: out[d] = relu(out[d] + sum 0.5*(att[e]+att[pair])*hc[src[e]])
// ---------------------------------------------------------------------------
__global__ __launch_bounds__(256) void gather_watt_relu(
    const int* __restrict__ off, const int* __restrict__ csr_src,
    const int* __restrict__ csr_eid, const float* __restrict__ att,
    const float* __restrict__ hc, float* __restrict__ out)
{
    const int t    = blockIdx.x * 256 + threadIdx.x;
    const int node = t >> 6;
    const int lane = t & 63;
    if (node >= N_NODES) return;
    const int beg = off[node];
    const int end = off[node + 1];
    const size_t o = (size_t)node * D + lane * 2;
    float2 acc = *(const float2*)&out[o];
    for (int j = beg; j < end; ++j) {
        const int s   = csr_src[j];
        const int eid = csr_eid[j];
        const int pr  = (eid < E_HALF) ? (eid + E_HALF) : (eid - E_HALF);
        const float w = 0.5f * (att[eid] + att[pr]);
        const float2 v = *(const float2*)&hc[(size_t)s * D + lane * 2];
        acc.x = fmaf(w, v.x, acc.x);
        acc.y = fmaf(w, v.y, acc.y);
    }
    acc.x = fmaxf(acc.x, 0.f);
    acc.y = fmaxf(acc.y, 0.f);
    *(float2*)&out[o] = acc;
}

// ---------------------------------------------------------------------------
// edge_logits: att[e] = sigmoid( tanh(A[src]+B[dst]) . we2 + gumbel(noise) )
// fast tanh: 1 - 2/(e^{2x}+1); correct limits at +-inf, no clamp needed.
// ---------------------------------------------------------------------------
__device__ __forceinline__ float fast_tanh(float v)
{
    const float e = __expf(2.f * v);
    return 1.f - 2.f / (e + 1.f);
}

__global__ __launch_bounds__(256) void edge_logits(
    const int* __restrict__ src, const int* __restrict__ dst,
    const float* __restrict__ A, const float* __restrict__ B,
    const float* __restrict__ we2, const float* __restrict__ noise_u,
    float* __restrict__ att)
{
    const int t    = blockIdx.x * 256 + threadIdx.x;
    const int e    = t >> 5;
    const int lane = t & 31;
    if (e >= N_EDGES) return;
    const int s = src[e];
    const int d = dst[e];
    const float4 a = *(const float4*)&A[(size_t)s * D + lane * 4];
    const float4 b = *(const float4*)&B[(size_t)d * D + lane * 4];
    const float4 w = *(const float4*)&we2[lane * 4];
    float p = fast_tanh(a.x + b.x) * w.x + fast_tanh(a.y + b.y) * w.y +
              fast_tanh(a.z + b.z) * w.z + fast_tanh(a.w + b.w) * w.w;
    #pragma unroll
    for (int off = 16; off >= 1; off >>= 1)
        p += __shfl_xor(p, off, 32);
    if (lane == 0) {
        const float u = noise_u[e];
        const float z = p + logf(u) - log1pf(-u);
        att[e] = 1.f / (1.f + __expf(-z));
    }
}

extern "C" void kernel_launch(void* const* d_in, const int* in_sizes, int n_in,
                              void* d_out, int out_size, void* d_ws, size_t ws_size,
                              hipStream_t stream)
{
    const float* x      = (const float*)d_in[0];
    const float* W1     = (const float*)d_in[1];
    const float* W2     = (const float*)d_in[2];
    const float* We1    = (const float*)d_in[3];
    const float* we2    = (const float*)d_in[4];
    const float* Wc1    = (const float*)d_in[5];
    const float* Wc2    = (const float*)d_in[6];
    const float* noiseu = (const float*)d_in[7];
    const int*   eidx   = (const int*)d_in[8];

    const int* src = eidx;
    const int* dst = eidx + N_EDGES;

    float* out = (float*)d_out;

    // workspace layout (float elements); total ~82 MB
    float* wsf = (float*)d_ws;
    float* h   = wsf;                  // [N,D]  x@W1, later A
    float* hc  = wsf +  6400000;       // [N,D]  x@Wc1
    float* emb = wsf + 12800000;       // [N,D]  x@W2 + agg, later B (in-place)
    float* att = wsf + 19200000;       // [E]
    int* ibase   = (int*)(wsf + 19600000);
    int* cnt     = ibase;              // [N]
    int* off     = ibase + 50000;      // [N+1]
    int* cursor  = ibase + 100001;     // [N]
    int* csr_src = ibase + 151296;     // [E] (16B aligned)
    int* csr_eid = csr_src + N_EDGES;  // [E]

    const int row_tiles = (N_NODES + 63) / 64;          // 782
    const int edge_blk  = (N_EDGES + 255) / 256;        // 1563
    const int node_blk  = (N_NODES * 64 + 255) / 256;   // 12500
    const int elog_blk  = (N_EDGES * 32 + 255) / 256;   // 50000

    // CSR build (independent of GEMMs)
    zero_kernel<<<(N_NODES + 255) / 256, 256, 0, stream>>>(cnt, N_NODES);
    hist_kernel<<<edge_blk, 256, 0, stream>>>(dst, cnt);
    scan_kernel<<<1, SCAN_T, 0, stream>>>(cnt, off, cursor);
    bucket_kernel<<<edge_blk, 256, 0, stream>>>(src, dst, cursor, csr_src, csr_eid);

    // K1: h = x@W1, emb = x@W2, hc = x@Wc1, out = x@Wc2  (x staged once)
    gemm_multi<4, 0><<<row_tiles, 256, 0, stream>>>(
        x, W1, W2, Wc1, Wc2, h, emb, hc, out);

    // K2: emb += gather-sum of h over incoming edges
    gather_sum<<<node_blk, 256, 0, stream>>>(off, csr_src, h, emb);

    // K3: A = relu(emb)@We1_top -> h ; B = relu(emb)@We1_bot -> emb (in-place)
    gemm_multi<2, 1><<<row_tiles, 256, 0, stream>>>(
        emb, We1, We1 + D * D, nullptr, nullptr, h, emb, nullptr, nullptr);

    // K4: att logits + gumbel-sigmoid
    edge_logits<<<elog_blk, 256, 0, stream>>>(src, dst, h, emb, we2, noiseu, att);

    // K5: out = relu(out + symmetrized-att-weighted gather of hc)
    gather_watt_relu<<<node_blk, 256, 0, stream>>>(off, csr_src, csr_eid, att, hc, out);
}

// Round 7
// 599.305 us; speedup vs baseline: 2.9952x; 1.2023x over previous
//
#include <hip/hip_runtime.h>
#include <math.h>

#define N_NODES 50000
#define N_EDGES 400000
#define E_HALF  200000
#define D 128

// ---------------------------------------------------------------------------
// gemm_multi: fp32 GEMM  O[g] = act(x) @ W[g], g = 0..NG-1 (act = relu if RELU_IN)
// x: [N,128] row-major, W: [128,128] row-major, O: [N,128].
// 256 threads, 64-row tile. x tile staged to LDS once (padded stride 132).
// W staged in 32-row k-chunks (16 KB) -> total LDS 50.2 KB -> 3 blocks/CU
// (12 waves/CU) instead of the 97 KB/1-block version (round-5 occupancy fix).
// Thread tile: 4 rows x 8 cols, cols split as [tx*4, tx*4+4) u [64+tx*4, ...)
// so ws reads are 16B-stride ds_read_b128 (2-way bank alias = free) instead
// of 32B-stride (4-way conflict, 1.28e7 extra cycles in round 5).
// In-place safe (O[g] == x): each block writes only rows it staged itself.
// ---------------------------------------------------------------------------
template <int NG, int RELU_IN>
__global__ __launch_bounds__(256, 3) void gemm_multi(
    const float* __restrict__ x,
    const float* __restrict__ W0, const float* __restrict__ W1,
    const float* __restrict__ W2, const float* __restrict__ W3,
    float* __restrict__ O0, float* __restrict__ O1,
    float* __restrict__ O2, float* __restrict__ O3)
{
    __shared__ float ws[32][128];     // 16 KB (one k-chunk of W)
    __shared__ float xs[64][132];     // 33.8 KB

    const float* Wg[4] = {W0, W1, W2, W3};
    float*       Og[4] = {O0, O1, O2, O3};

    const int tid  = threadIdx.x;
    const int row0 = blockIdx.x * 64;

    // stage x tile once
    for (int i = tid * 4; i < 64 * D; i += 256 * 4) {
        const int row = i >> 7;
        const int col = i & 127;
        const int r   = row0 + row;
        float4 v;
        if (r < N_NODES) {
            v = *(const float4*)&x[(size_t)r * D + col];
        } else {
            v = make_float4(0.f, 0.f, 0.f, 0.f);
        }
        if (RELU_IN) {
            v.x = fmaxf(v.x, 0.f); v.y = fmaxf(v.y, 0.f);
            v.z = fmaxf(v.z, 0.f); v.w = fmaxf(v.w, 0.f);
        }
        *(float4*)&xs[row][col] = v;
    }

    const int ty  = tid >> 4;         // 0..15
    const int tx  = tid & 15;         // 0..15
    const int r0  = ty * 4;
    const int c0a = tx * 4;           // first 4-col group
    const int c0b = 64 + tx * 4;      // second 4-col group

    #pragma unroll
    for (int g = 0; g < NG; ++g) {
        const float* W = Wg[g];

        float acc[4][8];
        #pragma unroll
        for (int r = 0; r < 4; ++r)
            #pragma unroll
            for (int c = 0; c < 8; ++c) acc[r][c] = 0.f;

        for (int kc = 0; kc < 4; ++kc) {        // 4 chunks of 32 k-rows
            __syncthreads();                    // xs staged / prev ws reads done
            for (int i = tid * 4; i < 32 * D; i += 256 * 4) {
                *(float4*)&ws[0][0 + i] = *(const float4*)&W[kc * 32 * D + i];
            }
            __syncthreads();

            const int kbase = kc * 32;
            #pragma unroll 4
            for (int k2 = 0; k2 < 32; ++k2) {
                const float4 wa = *(const float4*)&ws[k2][c0a];
                const float4 wb = *(const float4*)&ws[k2][c0b];
                const float wv[8] = {wa.x, wa.y, wa.z, wa.w,
                                     wb.x, wb.y, wb.z, wb.w};
                #pragma unroll
                for (int r = 0; r < 4; ++r) {
                    const float xv = xs[r0 + r][kbase + k2];
                    #pragma unroll
                    for (int c = 0; c < 8; ++c)
                        acc[r][c] = fmaf(xv, wv[c], acc[r][c]);
                }
            }
        }

        float* O = Og[g];
        #pragma unroll
        for (int r = 0; r < 4; ++r) {
            const int row = row0 + r0 + r;
            if (row < N_NODES) {
                float4 oa = make_float4(acc[r][0], acc[r][1], acc[r][2], acc[r][3]);
                float4 ob = make_float4(acc[r][4], acc[r][5], acc[r][6], acc[r][7]);
                *(float4*)&O[(size_t)row * D + c0a] = oa;
                *(float4*)&O[(size_t)row * D + c0b] = ob;
            }
        }
    }
}

// ---------------------------------------------------------------------------
// CSR build: zero -> histogram -> single-block scan -> bucket scatter
// ---------------------------------------------------------------------------
__global__ __launch_bounds__(256) void zero_kernel(int* __restrict__ p, int n)
{
    const int i = blockIdx.x * 256 + threadIdx.x;
    if (i < n) p[i] = 0;
}

__global__ __launch_bounds__(256) void hist_kernel(
    const int* __restrict__ dst, int* __restrict__ cnt)
{
    const int e = blockIdx.x * 256 + threadIdx.x;
    if (e < N_EDGES) atomicAdd(&cnt[dst[e]], 1);
}

#define SCAN_T 1024
__global__ __launch_bounds__(SCAN_T) void scan_kernel(
    const int* __restrict__ cnt, int* __restrict__ off, int* __restrict__ cursor)
{
    __shared__ int part[SCAN_T];
    const int tid  = threadIdx.x;
    const int per  = (N_NODES + SCAN_T - 1) / SCAN_T;   // 49
    const int base = tid * per;
    int s = 0;
    for (int i = 0; i < per; ++i) {
        const int idx = base + i;
        if (idx < N_NODES) s += cnt[idx];
    }
    part[tid] = s;
    __syncthreads();
    for (int d = 1; d < SCAN_T; d <<= 1) {
        const int v = (tid >= d) ? part[tid - d] : 0;
        __syncthreads();
        part[tid] += v;
        __syncthreads();
    }
    int run = part[tid] - s;   // exclusive prefix
    for (int i = 0; i < per; ++i) {
        const int idx = base + i;
        if (idx < N_NODES) {
            off[idx]    = run;
            cursor[idx] = run;
            run += cnt[idx];
        }
    }
    if (tid == SCAN_T - 1) off[N_NODES] = run;
}

__global__ __launch_bounds__(256) void bucket_kernel(
    const int* __restrict__ src, const int* __restrict__ dst,
    int* __restrict__ cursor, int* __restrict__ csr_src, int* __restrict__ csr_eid)
{
    const int e = blockIdx.x * 256 + threadIdx.x;
    if (e >= N_EDGES) return;
    const int pos = atomicAdd(&cursor[dst[e]], 1);
    csr_src[pos] = src[e];
    csr_eid[pos] = e;
}

// ---------------------------------------------------------------------------
// gather_sum: emb[d] += sum_{e: dst=d} h[src[e]]   (one wave/node, float2/lane)
// ---------------------------------------------------------------------------
__global__ __launch_bounds__(256) void gather_sum(
    const int* __restrict__ off, const int* __restrict__ csr_src,
    const float* __restrict__ h, float* __restrict__ emb)
{
    const int t    = blockIdx.x * 256 + threadIdx.x;
    const int node = t >> 6;
    const int lane = t & 63;
    if (node >= N_NODES) return;
    const int beg = off[node];
    const int end = off[node + 1];
    const size_t o = (size_t)node * D + lane * 2;
    float2 acc = *(const float2*)&emb[o];
    for (int j = beg; j < end; ++j) {
        const int s = csr_src[j];
        const float2 v = *(const float2*)&h[(size_t)s * D + lane * 2];
        acc.x += v.x; acc.y += v.y;
    }
    *(float2*)&emb[o] = acc;
}

// ---------------------------------------------------------------------------
// gather_watt_relu: out[d] = relu(out[d] + sum 0.5*(att[e]+att[pair])*hc[src[e]])
// ---------------------------------------------------------------------------
__global__ __launch_bounds__(256) void gather_watt_relu(
    const int* __restrict__ off, const int* __restrict__ csr_src,
    const int* __restrict__ csr_eid, const float* __restrict__ att,
    const float* __restrict__ hc, float* __restrict__ out)
{
    const int t    = blockIdx.x * 256 + threadIdx.x;
    const int node = t >> 6;
    const int lane = t & 63;
    if (node >= N_NODES) return;
    const int beg = off[node];
    const int end = off[node + 1];
    const size_t o = (size_t)node * D + lane * 2;
    float2 acc = *(const float2*)&out[o];
    for (int j = beg; j < end; ++j) {
        const int s   = csr_src[j];
        const int eid = csr_eid[j];
        const int pr  = (eid < E_HALF) ? (eid + E_HALF) : (eid - E_HALF);
        const float w = 0.5f * (att[eid] + att[pr]);
        const float2 v = *(const float2*)&hc[(size_t)s * D + lane * 2];
        acc.x = fmaf(w, v.x, acc.x);
        acc.y = fmaf(w, v.y, acc.y);
    }
    acc.x = fmaxf(acc.x, 0.f);
    acc.y = fmaxf(acc.y, 0.f);
    *(float2*)&out[o] = acc;
}

// ---------------------------------------------------------------------------
// edge_logits: att[e] = sigmoid( tanh(A[src]+B[dst]) . we2 + gumbel(noise) )
// fast tanh: 1 - 2/(e^{2x}+1); correct limits at +-inf, no clamp needed.
// ---------------------------------------------------------------------------
__device__ __forceinline__ float fast_tanh(float v)
{
    const float e = __expf(2.f * v);
    return 1.f - 2.f / (e + 1.f);
}

__global__ __launch_bounds__(256) void edge_logits(
    const int* __restrict__ src, const int* __restrict__ dst,
    const float* __restrict__ A, const float* __restrict__ B,
    const float* __restrict__ we2, const float* __restrict__ noise_u,
    float* __restrict__ att)
{
    const int t    = blockIdx.x * 256 + threadIdx.x;
    const int e    = t >> 5;
    const int lane = t & 31;
    if (e >= N_EDGES) return;
    const int s = src[e];
    const int d = dst[e];
    const float4 a = *(const float4*)&A[(size_t)s * D + lane * 4];
    const float4 b = *(const float4*)&B[(size_t)d * D + lane * 4];
    const float4 w = *(const float4*)&we2[lane * 4];
    float p = fast_tanh(a.x + b.x) * w.x + fast_tanh(a.y + b.y) * w.y +
              fast_tanh(a.z + b.z) * w.z + fast_tanh(a.w + b.w) * w.w;
    #pragma unroll
    for (int off = 16; off >= 1; off >>= 1)
        p += __shfl_xor(p, off, 32);
    if (lane == 0) {
        const float u = noise_u[e];
        const float z = p + logf(u) - log1pf(-u);
        att[e] = 1.f / (1.f + __expf(-z));
    }
}

extern "C" void kernel_launch(void* const* d_in, const int* in_sizes, int n_in,
                              void* d_out, int out_size, void* d_ws, size_t ws_size,
                              hipStream_t stream)
{
    const float* x      = (const float*)d_in[0];
    const float* W1     = (const float*)d_in[1];
    const float* W2     = (const float*)d_in[2];
    const float* We1    = (const float*)d_in[3];
    const float* we2    = (const float*)d_in[4];
    const float* Wc1    = (const float*)d_in[5];
    const float* Wc2    = (const float*)d_in[6];
    const float* noiseu = (const float*)d_in[7];
    const int*   eidx   = (const int*)d_in[8];

    const int* src = eidx;
    const int* dst = eidx + N_EDGES;

    float* out = (float*)d_out;

    // workspace layout (float elements); total ~82 MB
    float* wsf = (float*)d_ws;
    float* h   = wsf;                  // [N,D]  x@W1, later A
    float* hc  = wsf +  6400000;       // [N,D]  x@Wc1
    float* emb = wsf + 12800000;       // [N,D]  x@W2 + agg, later B (in-place)
    float* att = wsf + 19200000;       // [E]
    int* ibase   = (int*)(wsf + 19600000);
    int* cnt     = ibase;              // [N]
    int* off     = ibase + 50000;      // [N+1]
    int* cursor  = ibase + 100001;     // [N]
    int* csr_src = ibase + 151296;     // [E] (16B aligned)
    int* csr_eid = csr_src + N_EDGES;  // [E]

    const int row_tiles = (N_NODES + 63) / 64;          // 782
    const int edge_blk  = (N_EDGES + 255) / 256;        // 1563
    const int node_blk  = (N_NODES * 64 + 255) / 256;   // 12500
    const int elog_blk  = (N_EDGES * 32 + 255) / 256;   // 50000

    // CSR build (independent of GEMMs)
    zero_kernel<<<(N_NODES + 255) / 256, 256, 0, stream>>>(cnt, N_NODES);
    hist_kernel<<<edge_blk, 256, 0, stream>>>(dst, cnt);
    scan_kernel<<<1, SCAN_T, 0, stream>>>(cnt, off, cursor);
    bucket_kernel<<<edge_blk, 256, 0, stream>>>(src, dst, cursor, csr_src, csr_eid);

    // K1: h = x@W1, emb = x@W2, hc = x@Wc1, out = x@Wc2  (x staged once)
    gemm_multi<4, 0><<<row_tiles, 256, 0, stream>>>(
        x, W1, W2, Wc1, Wc2, h, emb, hc, out);

    // K2: emb += gather-sum of h over incoming edges
    gather_sum<<<node_blk, 256, 0, stream>>>(off, csr_src, h, emb);

    // K3: A = relu(emb)@We1_top -> h ; B = relu(emb)@We1_bot -> emb (in-place)
    gemm_multi<2, 1><<<row_tiles, 256, 0, stream>>>(
        emb, We1, We1 + D * D, nullptr, nullptr, h, emb, nullptr, nullptr);

    // K4: att logits + gumbel-sigmoid
    edge_logits<<<elog_blk, 256, 0, stream>>>(src, dst, h, emb, we2, noiseu, att);

    // K5: out = relu(out + symmetrized-att-weighted gather of hc)
    gather_watt_relu<<<node_blk, 256, 0, stream>>>(off, csr_src, csr_eid, att, hc, out);
}

// Round 13
// 495.189 us; speedup vs baseline: 3.6250x; 1.2103x over previous
//
#include <hip/hip_runtime.h>
#include <math.h>

#define N_NODES 50000
#define N_EDGES 400000
#define E_HALF  200000
#define D 128

// ---------------------------------------------------------------------------
// gemm_multi: fp32 GEMM  O[g] = act(x) @ W[g], g = 0..NG-1 (act = relu if RELU_IN)
// x: [N,128] row-major, W: [128,128] row-major, O: [N,128].
// 256 threads, 64-row tile. x tile staged to LDS once, TRANSPOSED (k-major):
// xt[k][row], stride 68 (16B-aligned for row-groups of 4, conflict-free b128
// reads: 4 distinct addrs/wave, 16-lane broadcast each). Inner loop per k:
// 1 ds_read_b128 (4 x-rows) + 2 ds_read_b128 (weights) feeding 32 FMAs
// (round-7: 4 scalar b32 x-reads -> LDS-latency-bound at VALUBusy 40%).
// W staged in 32-row k-chunks (16 KB). Total LDS 50 KB -> 3 blocks/CU.
// Staging write is 16-way bank-conflicted but one-time (~180cy/tile),
// amortized over 128 k-iters x NG gemms.
// In-place safe (O[g] == x): each block writes only rows it staged itself.
// ---------------------------------------------------------------------------
template <int NG, int RELU_IN>
__global__ __launch_bounds__(256, 3) void gemm_multi(
    const float* __restrict__ x,
    const float* __restrict__ W0, const float* __restrict__ W1,
    const float* __restrict__ W2, const float* __restrict__ W3,
    float* __restrict__ O0, float* __restrict__ O1,
    float* __restrict__ O2, float* __restrict__ O3)
{
    __shared__ float ws[32][128];     // 16 KB (one k-chunk of W)
    __shared__ float xt[128][68];     // 34 KB, transposed x tile: xt[k][row]

    const float* Wg[4] = {W0, W1, W2, W3};
    float*       Og[4] = {O0, O1, O2, O3};

    const int tid  = threadIdx.x;
    const int row0 = blockIdx.x * 64;

    // stage x tile once, transposed
    for (int i = tid * 4; i < 64 * D; i += 256 * 4) {
        const int row = i >> 7;
        const int col = i & 127;
        const int r   = row0 + row;
        float4 v;
        if (r < N_NODES) {
            v = *(const float4*)&x[(size_t)r * D + col];
        } else {
            v = make_float4(0.f, 0.f, 0.f, 0.f);
        }
        if (RELU_IN) {
            v.x = fmaxf(v.x, 0.f); v.y = fmaxf(v.y, 0.f);
            v.z = fmaxf(v.z, 0.f); v.w = fmaxf(v.w, 0.f);
        }
        xt[col + 0][row] = v.x;
        xt[col + 1][row] = v.y;
        xt[col + 2][row] = v.z;
        xt[col + 3][row] = v.w;
    }

    const int ty  = tid >> 4;         // 0..15
    const int tx  = tid & 15;         // 0..15
    const int r0  = ty * 4;
    const int c0a = tx * 4;           // first 4-col group
    const int c0b = 64 + tx * 4;      // second 4-col group

    #pragma unroll
    for (int g = 0; g < NG; ++g) {
        const float* W = Wg[g];

        float acc[4][8];
        #pragma unroll
        for (int r = 0; r < 4; ++r)
            #pragma unroll
            for (int c = 0; c < 8; ++c) acc[r][c] = 0.f;

        for (int kc = 0; kc < 4; ++kc) {        // 4 chunks of 32 k-rows
            __syncthreads();                    // xt staged / prev ws reads done
            for (int i = tid * 4; i < 32 * D; i += 256 * 4) {
                *(float4*)&ws[0][0 + i] = *(const float4*)&W[kc * 32 * D + i];
            }
            __syncthreads();

            const int kbase = kc * 32;
            #pragma unroll 4
            for (int k2 = 0; k2 < 32; ++k2) {
                const float4 wa = *(const float4*)&ws[k2][c0a];
                const float4 wb = *(const float4*)&ws[k2][c0b];
                const float4 xv = *(const float4*)&xt[kbase + k2][r0];
                const float wv[8] = {wa.x, wa.y, wa.z, wa.w,
                                     wb.x, wb.y, wb.z, wb.w};
                const float xr[4] = {xv.x, xv.y, xv.z, xv.w};
                #pragma unroll
                for (int r = 0; r < 4; ++r) {
                    #pragma unroll
                    for (int c = 0; c < 8; ++c)
                        acc[r][c] = fmaf(xr[r], wv[c], acc[r][c]);
                }
            }
        }

        float* O = Og[g];
        #pragma unroll
        for (int r = 0; r < 4; ++r) {
            const int row = row0 + r0 + r;
            if (row < N_NODES) {
                float4 oa = make_float4(acc[r][0], acc[r][1], acc[r][2], acc[r][3]);
                float4 ob = make_float4(acc[r][4], acc[r][5], acc[r][6], acc[r][7]);
                *(float4*)&O[(size_t)row * D + c0a] = oa;
                *(float4*)&O[(size_t)row * D + c0b] = ob;
            }
        }
    }
}

// ---------------------------------------------------------------------------
// CSR build: zero -> histogram -> 3-stage scan -> bucket scatter
// (round-7: single-block scan_kernel was 124us, uncoalesced latency-bound)
// ---------------------------------------------------------------------------
__global__ __launch_bounds__(256) void zero_kernel(int* __restrict__ p, int n)
{
    const int i = blockIdx.x * 256 + threadIdx.x;
    if (i < n) p[i] = 0;
}

__global__ __launch_bounds__(256) void hist_kernel(
    const int* __restrict__ dst, int* __restrict__ cnt)
{
    const int e = blockIdx.x * 256 + threadIdx.x;
    if (e < N_EDGES) atomicAdd(&cnt[dst[e]], 1);
}

#define SCAN_NB 196   // ceil(50000/256)

// stage 1: per-block exclusive scan of cnt; block totals to bsum
__global__ __launch_bounds__(256) void scan_partial(
    const int* __restrict__ cnt, int* __restrict__ exc, int* __restrict__ bsum)
{
    __shared__ int sh[256];
    const int t   = threadIdx.x;
    const int idx = blockIdx.x * 256 + t;
    const int v   = (idx < N_NODES) ? cnt[idx] : 0;
    sh[t] = v;
    __syncthreads();
    #pragma unroll
    for (int d = 1; d < 256; d <<= 1) {
        const int tv = (t >= d) ? sh[t - d] : 0;
        __syncthreads();
        sh[t] += tv;
        __syncthreads();
    }
    if (idx < N_NODES) exc[idx] = sh[t] - v;
    if (t == 255) bsum[blockIdx.x] = sh[255];
}

// stage 2: one block scans the block totals
__global__ __launch_bounds__(256) void scan_block(
    const int* __restrict__ bsum, int* __restrict__ bscan)
{
    __shared__ int sh[256];
    const int t = threadIdx.x;
    const int v = (t < SCAN_NB) ? bsum[t] : 0;
    sh[t] = v;
    __syncthreads();
    #pragma unroll
    for (int d = 1; d < 256; d <<= 1) {
        const int tv = (t >= d) ? sh[t - d] : 0;
        __syncthreads();
        sh[t] += tv;
        __syncthreads();
    }
    if (t < SCAN_NB) bscan[t] = sh[t] - v;
}

// stage 3: add block offsets, emit off + cursor; off[N] is the edge total
__global__ __launch_bounds__(256) void scan_final(
    const int* __restrict__ exc, const int* __restrict__ bscan,
    int* __restrict__ off, int* __restrict__ cursor)
{
    const int idx = blockIdx.x * 256 + threadIdx.x;
    if (idx < N_NODES) {
        const int o = exc[idx] + bscan[blockIdx.x];
        off[idx]    = o;
        cursor[idx] = o;
    }
    if (idx == 0) off[N_NODES] = N_EDGES;
}

__global__ __launch_bounds__(256) void bucket_kernel(
    const int* __restrict__ src, const int* __restrict__ dst,
    int* __restrict__ cursor, int* __restrict__ csr_src, int* __restrict__ csr_eid)
{
    const int e = blockIdx.x * 256 + threadIdx.x;
    if (e >= N_EDGES) return;
    const int pos = atomicAdd(&cursor[dst[e]], 1);
    csr_src[pos] = src[e];
    csr_eid[pos] = e;
}

// ---------------------------------------------------------------------------
// gather_sum: emb[d] += sum_{e: dst=d} h[src[e]]   (one wave/node, float2/lane)
// ---------------------------------------------------------------------------
__global__ __launch_bounds__(256) void gather_sum(
    const int* __restrict__ off, const int* __restrict__ csr_src,
    const float* __restrict__ h, float* __restrict__ emb)
{
    const int t    = blockIdx.x * 256 + threadIdx.x;
    const int node = t >> 6;
    const int lane = t & 63;
    if (node >= N_NODES) return;
    const int beg = off[node];
    const int end = off[node + 1];
    const size_t o = (size_t)node * D + lane * 2;
    float2 acc = *(const float2*)&emb[o];
    for (int j = beg; j < end; ++j) {
        const int s = csr_src[j];
        const float2 v = *(const float2*)&h[(size_t)s * D + lane * 2];
        acc.x += v.x; acc.y += v.y;
    }
    *(float2*)&emb[o] = acc;
}

// ---------------------------------------------------------------------------
// gather_watt_relu: out[d] = relu(out[d] + sum 0.5*(att[e]+att[pair])*hc[src[e]])
// ---------------------------------------------------------------------------
__global__ __launch_bounds__(256) void gather_watt_relu(
    const int* __restrict__ off, const int* __restrict__ csr_src,
    const int* __restrict__ csr_eid, const float* __restrict__ att,
    const float* __restrict__ hc, float* __restrict__ out)
{
    const int t    = blockIdx.x * 256 + threadIdx.x;
    const int node = t >> 6;
    const int lane = t & 63;
    if (node >= N_NODES) return;
    const int beg = off[node];
    const int end = off[node + 1];
    const size_t o = (size_t)node * D + lane * 2;
    float2 acc = *(const float2*)&out[o];
    for (int j = beg; j < end; ++j) {
        const int s   = csr_src[j];
        const int eid = csr_eid[j];
        const int pr  = (eid < E_HALF) ? (eid + E_HALF) : (eid - E_HALF);
        const float w = 0.5f * (att[eid] + att[pr]);
        const float2 v = *(const float2*)&hc[(size_t)s * D + lane * 2];
        acc.x = fmaf(w, v.x, acc.x);
        acc.y = fmaf(w, v.y, acc.y);
    }
    acc.x = fmaxf(acc.x, 0.f);
    acc.y = fmaxf(acc.y, 0.f);
    *(float2*)&out[o] = acc;
}

// ---------------------------------------------------------------------------
// edge_logits: att[e] = sigmoid( tanh(A[src]+B[dst]) . we2 + gumbel(noise) )
// fast tanh: 1 - 2/(e^{2x}+1); correct limits at +-inf, no clamp needed.
// ---------------------------------------------------------------------------
__device__ __forceinline__ float fast_tanh(float v)
{
    const float e = __expf(2.f * v);
    return 1.f - 2.f / (e + 1.f);
}

__global__ __launch_bounds__(256) void edge_logits(
    const int* __restrict__ src, const int* __restrict__ dst,
    const float* __restrict__ A, const float* __restrict__ B,
    const float* __restrict__ we2, const float* __restrict__ noise_u,
    float* __restrict__ att)
{
    const int t    = blockIdx.x * 256 + threadIdx.x;
    const int e    = t >> 5;
    const int lane = t & 31;
    if (e >= N_EDGES) return;
    const int s = src[e];
    const int d = dst[e];
    const float4 a = *(const float4*)&A[(size_t)s * D + lane * 4];
    const float4 b = *(const float4*)&B[(size_t)d * D + lane * 4];
    const float4 w = *(const float4*)&we2[lane * 4];
    float p = fast_tanh(a.x + b.x) * w.x + fast_tanh(a.y + b.y) * w.y +
              fast_tanh(a.z + b.z) * w.z + fast_tanh(a.w + b.w) * w.w;
    #pragma unroll
    for (int off = 16; off >= 1; off >>= 1)
        p += __shfl_xor(p, off, 32);
    if (lane == 0) {
        const float u = noise_u[e];
        const float z = p + logf(u) - log1pf(-u);
        att[e] = 1.f / (1.f + __expf(-z));
    }
}

extern "C" void kernel_launch(void* const* d_in, const int* in_sizes, int n_in,
                              void* d_out, int out_size, void* d_ws, size_t ws_size,
                              hipStream_t stream)
{
    const float* x      = (const float*)d_in[0];
    const float* W1     = (const float*)d_in[1];
    const float* W2     = (const float*)d_in[2];
    const float* We1    = (const float*)d_in[3];
    const float* we2    = (const float*)d_in[4];
    const float* Wc1    = (const float*)d_in[5];
    const float* Wc2    = (const float*)d_in[6];
    const float* noiseu = (const float*)d_in[7];
    const int*   eidx   = (const int*)d_in[8];

    const int* src = eidx;
    const int* dst = eidx + N_EDGES;

    float* out = (float*)d_out;

    // workspace layout (float elements); total ~83 MB
    float* wsf = (float*)d_ws;
    float* h   = wsf;                  // [N,D]  x@W1, later A
    float* hc  = wsf +  6400000;       // [N,D]  x@Wc1
    float* emb = wsf + 12800000;       // [N,D]  x@W2 + agg, later B (in-place)
    float* att = wsf + 19200000;       // [E]
    int* ibase   = (int*)(wsf + 19600000);
    int* cnt     = ibase;              // [N]
    int* off     = ibase + 50000;      // [N+1]
    int* cursor  = ibase + 100001;     // [N]
    int* exc     = ibase + 150001;     // [N]
    int* bsum    = ibase + 200001;     // [SCAN_NB]
    int* bscan   = ibase + 200257;     // [SCAN_NB]
    int* csr_src = ibase + 262144;     // [E] (aligned)
    int* csr_eid = csr_src + N_EDGES;  // [E]

    const int row_tiles = (N_NODES + 63) / 64;          // 782
    const int edge_blk  = (N_EDGES + 255) / 256;        // 1563
    const int node_blk  = (N_NODES * 64 + 255) / 256;   // 12500
    const int elog_blk  = (N_EDGES * 32 + 255) / 256;   // 50000

    // CSR build (independent of GEMMs)
    zero_kernel<<<(N_NODES + 255) / 256, 256, 0, stream>>>(cnt, N_NODES);
    hist_kernel<<<edge_blk, 256, 0, stream>>>(dst, cnt);
    scan_partial<<<SCAN_NB, 256, 0, stream>>>(cnt, exc, bsum);
    scan_block<<<1, 256, 0, stream>>>(bsum, bscan);
    scan_final<<<SCAN_NB, 256, 0, stream>>>(exc, bscan, off, cursor);
    bucket_kernel<<<edge_blk, 256, 0, stream>>>(src, dst, cursor, csr_src, csr_eid);

    // K1: h = x@W1, emb = x@W2, hc = x@Wc1, out = x@Wc2  (x staged once)
    gemm_multi<4, 0><<<row_tiles, 256, 0, stream>>>(
        x, W1, W2, Wc1, Wc2, h, emb, hc, out);

    // K2: emb += gather-sum of h over incoming edges
    gather_sum<<<node_blk, 256, 0, stream>>>(off, csr_src, h, emb);

    // K3: A = relu(emb)@We1_top -> h ; B = relu(emb)@We1_bot -> emb (in-place)
    gemm_multi<2, 1><<<row_tiles, 256, 0, stream>>>(
        emb, We1, We1 + D * D, nullptr, nullptr, h, emb, nullptr, nullptr);

    // K4: att logits + gumbel-sigmoid
    edge_logits<<<elog_blk, 256, 0, stream>>>(src, dst, h, emb, we2, noiseu, att);

    // K5: out = relu(out + symmetrized-att-weighted gather of hc)
    gather_watt_relu<<<node_blk, 256, 0, stream>>>(off, csr_src, csr_eid, att, hc, out);
}

// Round 14
// 479.350 us; speedup vs baseline: 3.7448x; 1.0330x over previous
//
#include <hip/hip_runtime.h>
#include <math.h>

#define N_NODES 50000
#define N_EDGES 400000
#define E_HALF  200000
#define D 128

// ---------------------------------------------------------------------------
// gemm_multi: fp32 GEMM  O[g] = act(x) @ W[g], g = 0..NG-1 (act = relu if RELU_IN)
// x: [N,128] row-major, W: [128,128] row-major, O: [N,128].
//
// Round-13 post-mortem: kernel is LDS-PIPE-THROUGHPUT bound (3 b128/32 FMA
// per wave; 12 waves x 36cy = 432 LDS cyc vs 192 VALU cyc per k2 per CU;
// model postdicts the measured 126us). Fix: amortize LDS reads over more
// FMAs -> 8x8 per-thread register tile:
//   256 threads, 128-row tile; thread (ty,tx) owns rows ty*8..+8,
//   cols [tx*4,tx*4+4) u [64+tx*4, ...). Per k: 4 ds_read_b128
//   (2 W-cols split 64 apart -> 2-way free alias; 2 x-row quads ->
//   4-addr 16-lane broadcast, conflict-free) feed 64 FMAs (16 FMA/read
//   vs 10.7). LDS: ws[16][128] 8KB + xt[128][132] 66KB = 74KB ->
//   2 blocks/CU (8 waves). Predicted LDS 384 vs VALU 256 cyc/k2/CU.
// Staging write is 16-way bank-conflicted but one-time (~3e6 cyc/dispatch
// ~= 5us, same staged volume as round 13).
// In-place safe (O[g] == x): each block writes only rows it staged itself.
// ---------------------------------------------------------------------------
template <int NG, int RELU_IN>
__global__ __launch_bounds__(256) void gemm_multi(
    const float* __restrict__ x,
    const float* __restrict__ W0, const float* __restrict__ W1,
    const float* __restrict__ W2, const float* __restrict__ W3,
    float* __restrict__ O0, float* __restrict__ O1,
    float* __restrict__ O2, float* __restrict__ O3)
{
    __shared__ float ws[16][128];     // 8 KB (one k-chunk of W)
    __shared__ float xt[128][132];    // 66 KB, transposed x tile: xt[k][row]

    const float* Wg[4] = {W0, W1, W2, W3};
    float*       Og[4] = {O0, O1, O2, O3};

    const int tid  = threadIdx.x;
    const int row0 = blockIdx.x * 128;

    // stage 128-row x tile once, transposed (k-major)
    for (int i = tid * 4; i < 128 * D; i += 256 * 4) {
        const int row = i >> 7;
        const int col = i & 127;
        const int r   = row0 + row;
        float4 v;
        if (r < N_NODES) {
            v = *(const float4*)&x[(size_t)r * D + col];
        } else {
            v = make_float4(0.f, 0.f, 0.f, 0.f);
        }
        if (RELU_IN) {
            v.x = fmaxf(v.x, 0.f); v.y = fmaxf(v.y, 0.f);
            v.z = fmaxf(v.z, 0.f); v.w = fmaxf(v.w, 0.f);
        }
        xt[col + 0][row] = v.x;
        xt[col + 1][row] = v.y;
        xt[col + 2][row] = v.z;
        xt[col + 3][row] = v.w;
    }

    const int ty  = tid >> 4;         // 0..15
    const int tx  = tid & 15;         // 0..15
    const int r0  = ty * 8;           // 8 rows per thread
    const int c0a = tx * 4;           // first 4-col group
    const int c0b = 64 + tx * 4;      // second 4-col group

    #pragma unroll
    for (int g = 0; g < NG; ++g) {
        const float* W = Wg[g];

        float acc[8][8];
        #pragma unroll
        for (int r = 0; r < 8; ++r)
            #pragma unroll
            for (int c = 0; c < 8; ++c) acc[r][c] = 0.f;

        for (int kc = 0; kc < 8; ++kc) {        // 8 chunks of 16 k-rows
            __syncthreads();                    // xt staged / prev ws reads done
            for (int i = tid * 4; i < 16 * D; i += 256 * 4) {   // 2 iters
                *(float4*)&ws[0][0 + i] = *(const float4*)&W[kc * 16 * D + i];
            }
            __syncthreads();

            const int kbase = kc * 16;
            #pragma unroll 4
            for (int k2 = 0; k2 < 16; ++k2) {
                const float4 wa = *(const float4*)&ws[k2][c0a];
                const float4 wb = *(const float4*)&ws[k2][c0b];
                const float4 x0 = *(const float4*)&xt[kbase + k2][r0];
                const float4 x1 = *(const float4*)&xt[kbase + k2][r0 + 4];
                const float wv[8] = {wa.x, wa.y, wa.z, wa.w,
                                     wb.x, wb.y, wb.z, wb.w};
                const float xr[8] = {x0.x, x0.y, x0.z, x0.w,
                                     x1.x, x1.y, x1.z, x1.w};
                #pragma unroll
                for (int r = 0; r < 8; ++r) {
                    #pragma unroll
                    for (int c = 0; c < 8; ++c)
                        acc[r][c] = fmaf(xr[r], wv[c], acc[r][c]);
                }
            }
        }

        float* O = Og[g];
        #pragma unroll
        for (int r = 0; r < 8; ++r) {
            const int row = row0 + r0 + r;
            if (row < N_NODES) {
                float4 oa = make_float4(acc[r][0], acc[r][1], acc[r][2], acc[r][3]);
                float4 ob = make_float4(acc[r][4], acc[r][5], acc[r][6], acc[r][7]);
                *(float4*)&O[(size_t)row * D + c0a] = oa;
                *(float4*)&O[(size_t)row * D + c0b] = ob;
            }
        }
    }
}

// ---------------------------------------------------------------------------
// CSR build: zero -> histogram -> 3-stage scan -> bucket scatter
// (round-13: 3-stage scan verified, scan gone from top-5)
// ---------------------------------------------------------------------------
__global__ __launch_bounds__(256) void zero_kernel(int* __restrict__ p, int n)
{
    const int i = blockIdx.x * 256 + threadIdx.x;
    if (i < n) p[i] = 0;
}

__global__ __launch_bounds__(256) void hist_kernel(
    const int* __restrict__ dst, int* __restrict__ cnt)
{
    const int e = blockIdx.x * 256 + threadIdx.x;
    if (e < N_EDGES) atomicAdd(&cnt[dst[e]], 1);
}

#define SCAN_NB 196   // ceil(50000/256)

// stage 1: per-block exclusive scan of cnt; block totals to bsum
__global__ __launch_bounds__(256) void scan_partial(
    const int* __restrict__ cnt, int* __restrict__ exc, int* __restrict__ bsum)
{
    __shared__ int sh[256];
    const int t   = threadIdx.x;
    const int idx = blockIdx.x * 256 + t;
    const int v   = (idx < N_NODES) ? cnt[idx] : 0;
    sh[t] = v;
    __syncthreads();
    #pragma unroll
    for (int d = 1; d < 256; d <<= 1) {
        const int tv = (t >= d) ? sh[t - d] : 0;
        __syncthreads();
        sh[t] += tv;
        __syncthreads();
    }
    if (idx < N_NODES) exc[idx] = sh[t] - v;
    if (t == 255) bsum[blockIdx.x] = sh[255];
}

// stage 2: one block scans the block totals
__global__ __launch_bounds__(256) void scan_block(
    const int* __restrict__ bsum, int* __restrict__ bscan)
{
    __shared__ int sh[256];
    const int t = threadIdx.x;
    const int v = (t < SCAN_NB) ? bsum[t] : 0;
    sh[t] = v;
    __syncthreads();
    #pragma unroll
    for (int d = 1; d < 256; d <<= 1) {
        const int tv = (t >= d) ? sh[t - d] : 0;
        __syncthreads();
        sh[t] += tv;
        __syncthreads();
    }
    if (t < SCAN_NB) bscan[t] = sh[t] - v;
}

// stage 3: add block offsets, emit off + cursor; off[N] is the edge total
__global__ __launch_bounds__(256) void scan_final(
    const int* __restrict__ exc, const int* __restrict__ bscan,
    int* __restrict__ off, int* __restrict__ cursor)
{
    const int idx = blockIdx.x * 256 + threadIdx.x;
    if (idx < N_NODES) {
        const int o = exc[idx] + bscan[blockIdx.x];
        off[idx]    = o;
        cursor[idx] = o;
    }
    if (idx == 0) off[N_NODES] = N_EDGES;
}

__global__ __launch_bounds__(256) void bucket_kernel(
    const int* __restrict__ src, const int* __restrict__ dst,
    int* __restrict__ cursor, int* __restrict__ csr_src, int* __restrict__ csr_eid)
{
    const int e = blockIdx.x * 256 + threadIdx.x;
    if (e >= N_EDGES) return;
    const int pos = atomicAdd(&cursor[dst[e]], 1);
    csr_src[pos] = src[e];
    csr_eid[pos] = e;
}

// ---------------------------------------------------------------------------
// gather_sum: emb[d] += sum_{e: dst=d} h[src[e]]   (one wave/node, float2/lane)
// ---------------------------------------------------------------------------
__global__ __launch_bounds__(256) void gather_sum(
    const int* __restrict__ off, const int* __restrict__ csr_src,
    const float* __restrict__ h, float* __restrict__ emb)
{
    const int t    = blockIdx.x * 256 + threadIdx.x;
    const int node = t >> 6;
    const int lane = t & 63;
    if (node >= N_NODES) return;
    const int beg = off[node];
    const int end = off[node + 1];
    const size_t o = (size_t)node * D + lane * 2;
    float2 acc = *(const float2*)&emb[o];
    for (int j = beg; j < end; ++j) {
        const int s = csr_src[j];
        const float2 v = *(const float2*)&h[(size_t)s * D + lane * 2];
        acc.x += v.x; acc.y += v.y;
    }
    *(float2*)&emb[o] = acc;
}

// ---------------------------------------------------------------------------
// gather_watt_relu: out[d] = relu(out[d] + sum 0.5*(att[e]+att[pair])*hc[src[e]])
// ---------------------------------------------------------------------------
__global__ __launch_bounds__(256) void gather_watt_relu(
    const int* __restrict__ off, const int* __restrict__ csr_src,
    const int* __restrict__ csr_eid, const float* __restrict__ att,
    const float* __restrict__ hc, float* __restrict__ out)
{
    const int t    = blockIdx.x * 256 + threadIdx.x;
    const int node = t >> 6;
    const int lane = t & 63;
    if (node >= N_NODES) return;
    const int beg = off[node];
    const int end = off[node + 1];
    const size_t o = (size_t)node * D + lane * 2;
    float2 acc = *(const float2*)&out[o];
    for (int j = beg; j < end; ++j) {
        const int s   = csr_src[j];
        const int eid = csr_eid[j];
        const int pr  = (eid < E_HALF) ? (eid + E_HALF) : (eid - E_HALF);
        const float w = 0.5f * (att[eid] + att[pr]);
        const float2 v = *(const float2*)&hc[(size_t)s * D + lane * 2];
        acc.x = fmaf(w, v.x, acc.x);
        acc.y = fmaf(w, v.y, acc.y);
    }
    acc.x = fmaxf(acc.x, 0.f);
    acc.y = fmaxf(acc.y, 0.f);
    *(float2*)&out[o] = acc;
}

// ---------------------------------------------------------------------------
// edge_logits: att[e] = sigmoid( tanh(A[src]+B[dst]) . we2 + gumbel(noise) )
// fast tanh: 1 - 2/(e^{2x}+1); correct limits at +-inf, no clamp needed.
// ---------------------------------------------------------------------------
__device__ __forceinline__ float fast_tanh(float v)
{
    const float e = __expf(2.f * v);
    return 1.f - 2.f / (e + 1.f);
}

__global__ __launch_bounds__(256) void edge_logits(
    const int* __restrict__ src, const int* __restrict__ dst,
    const float* __restrict__ A, const float* __restrict__ B,
    const float* __restrict__ we2, const float* __restrict__ noise_u,
    float* __restrict__ att)
{
    const int t    = blockIdx.x * 256 + threadIdx.x;
    const int e    = t >> 5;
    const int lane = t & 31;
    if (e >= N_EDGES) return;
    const int s = src[e];
    const int d = dst[e];
    const float4 a = *(const float4*)&A[(size_t)s * D + lane * 4];
    const float4 b = *(const float4*)&B[(size_t)d * D + lane * 4];
    const float4 w = *(const float4*)&we2[lane * 4];
    float p = fast_tanh(a.x + b.x) * w.x + fast_tanh(a.y + b.y) * w.y +
              fast_tanh(a.z + b.z) * w.z + fast_tanh(a.w + b.w) * w.w;
    #pragma unroll
    for (int off = 16; off >= 1; off >>= 1)
        p += __shfl_xor(p, off, 32);
    if (lane == 0) {
        const float u = noise_u[e];
        const float z = p + logf(u) - log1pf(-u);
        att[e] = 1.f / (1.f + __expf(-z));
    }
}

extern "C" void kernel_launch(void* const* d_in, const int* in_sizes, int n_in,
                              void* d_out, int out_size, void* d_ws, size_t ws_size,
                              hipStream_t stream)
{
    const float* x      = (const float*)d_in[0];
    const float* W1     = (const float*)d_in[1];
    const float* W2     = (const float*)d_in[2];
    const float* We1    = (const float*)d_in[3];
    const float* we2    = (const float*)d_in[4];
    const float* Wc1    = (const float*)d_in[5];
    const float* Wc2    = (const float*)d_in[6];
    const float* noiseu = (const float*)d_in[7];
    const int*   eidx   = (const int*)d_in[8];

    const int* src = eidx;
    const int* dst = eidx + N_EDGES;

    float* out = (float*)d_out;

    // workspace layout (float elements); total ~83 MB
    float* wsf = (float*)d_ws;
    float* h   = wsf;                  // [N,D]  x@W1, later A
    float* hc  = wsf +  6400000;       // [N,D]  x@Wc1
    float* emb = wsf + 12800000;       // [N,D]  x@W2 + agg, later B (in-place)
    float* att = wsf + 19200000;       // [E]
    int* ibase   = (int*)(wsf + 19600000);
    int* cnt     = ibase;              // [N]
    int* off     = ibase + 50000;      // [N+1]
    int* cursor  = ibase + 100001;     // [N]
    int* exc     = ibase + 150001;     // [N]
    int* bsum    = ibase + 200001;     // [SCAN_NB]
    int* bscan   = ibase + 200257;     // [SCAN_NB]
    int* csr_src = ibase + 262144;     // [E] (aligned)
    int* csr_eid = csr_src + N_EDGES;  // [E]

    const int row_tiles = (N_NODES + 127) / 128;        // 391
    const int edge_blk  = (N_EDGES + 255) / 256;        // 1563
    const int node_blk  = (N_NODES * 64 + 255) / 256;   // 12500
    const int elog_blk  = (N_EDGES * 32 + 255) / 256;   // 50000

    // CSR build (independent of GEMMs)
    zero_kernel<<<(N_NODES + 255) / 256, 256, 0, stream>>>(cnt, N_NODES);
    hist_kernel<<<edge_blk, 256, 0, stream>>>(dst, cnt);
    scan_partial<<<SCAN_NB, 256, 0, stream>>>(cnt, exc, bsum);
    scan_block<<<1, 256, 0, stream>>>(bsum, bscan);
    scan_final<<<SCAN_NB, 256, 0, stream>>>(exc, bscan, off, cursor);
    bucket_kernel<<<edge_blk, 256, 0, stream>>>(src, dst, cursor, csr_src, csr_eid);

    // K1: h = x@W1, emb = x@W2, hc = x@Wc1, out = x@Wc2  (x staged once)
    gemm_multi<4, 0><<<row_tiles, 256, 0, stream>>>(
        x, W1, W2, Wc1, Wc2, h, emb, hc, out);

    // K2: emb += gather-sum of h over incoming edges
    gather_sum<<<node_blk, 256, 0, stream>>>(off, csr_src, h, emb);

    // K3: A = relu(emb)@We1_top -> h ; B = relu(emb)@We1_bot -> emb (in-place)
    gemm_multi<2, 1><<<row_tiles, 256, 0, stream>>>(
        emb, We1, We1 + D * D, nullptr, nullptr, h, emb, nullptr, nullptr);

    // K4: att logits + gumbel-sigmoid
    edge_logits<<<elog_blk, 256, 0, stream>>>(src, dst, h, emb, we2, noiseu, att);

    // K5: out = relu(out + symmetrized-att-weighted gather of hc)
    gather_watt_relu<<<node_blk, 256, 0, stream>>>(off, csr_src, csr_eid, att, hc, out);
}